// Round 2
// baseline (494.395 us; speedup 1.0000x reference)
//
#include <hip/hip_runtime.h>
#include <hip/hip_bf16.h>

typedef __bf16 bf16x8 __attribute__((ext_vector_type(8)));
typedef __bf16 bf16x4 __attribute__((ext_vector_type(4)));
typedef float  f32x4  __attribute__((ext_vector_type(4)));

// ---------------------------------------------------------------------------
// Kernel 1: prep
//  blocks [0,256):   U,V — block = (image n, 16-object chunk); cells in LDS
//  blocks [256,320): Qb  — ques @ g_w1[132:388) + g_b1
//  blocks [320,368): bf16 transpose of g_w2/g_w3/g_w4 via LDS 64x64 tiles
// ---------------------------------------------------------------------------
__global__ __launch_bounds__(256) void prep_kernel(
    const float* __restrict__ img, const float* __restrict__ ques,
    const float* __restrict__ g_w1, const float* __restrict__ g_b1,
    const float* __restrict__ g_w2, const float* __restrict__ g_w3,
    const float* __restrict__ g_w4,
    float* __restrict__ U, float* __restrict__ V, float* __restrict__ Qb,
    __bf16* __restrict__ W2t, __bf16* __restrict__ W3t, __bf16* __restrict__ W4t) {
  __shared__ float smem[64 * 65];   // 16.6 KB, reused by all branches
  const int blk = blockIdx.x;
  const int t = threadIdx.x;

  if (blk < 256) {
    const int n = blk >> 2, obase = (blk & 3) * 16;
    // stage cells[d][o] for d in [0,66), o in [obase, obase+16)
    for (int idx = t; idx < 66 * 16; idx += 256) {
      const int c = idx >> 4, o = obase + (idx & 15);
      float v;
      if (c < 64)      v = img[n * 4096 + c * 64 + o];
      else if (c == 64) v = (float)(o >> 3);
      else              v = (float)(o & 7);
      smem[idx] = v;
    }
    __syncthreads();
    float u[16], vv[16];
#pragma unroll
    for (int o = 0; o < 16; ++o) { u[o] = 0.f; vv[o] = 0.f; }
    for (int d = 0; d < 66; ++d) {
      const float wu = g_w1[d * 256 + t];
      const float wv = g_w1[(66 + d) * 256 + t];
#pragma unroll
      for (int o = 0; o < 16; ++o) {
        const float cc = smem[d * 16 + o];
        u[o]  += cc * wu;
        vv[o] += cc * wv;
      }
    }
#pragma unroll
    for (int o = 0; o < 16; ++o) {
      U[(size_t)(n * 64 + obase + o) * 256 + t] = u[o];
      V[(size_t)(n * 64 + obase + o) * 256 + t] = vv[o];
    }
  } else if (blk < 320) {
    const int n = blk - 256;
    smem[t] = ques[n * 256 + t];
    __syncthreads();
    float s = g_b1[t];
    for (int e = 0; e < 256; ++e) s += smem[e] * g_w1[(132 + e) * 256 + t];
    Qb[n * 256 + t] = s;
  } else {
    const int b2 = blk - 320;             // 0..47
    const int wsel = b2 >> 4;             // weight select
    const int tile = b2 & 15;             // 4x4 grid of 64x64 tiles
    const int r0 = (tile >> 2) * 64, c0 = (tile & 3) * 64;
    const float* W = (wsel == 0) ? g_w2 : (wsel == 1) ? g_w3 : g_w4;
    __bf16* Wt    = (wsel == 0) ? W2t  : (wsel == 1) ? W3t  : W4t;
    const int col = t & 63, rb = (t >> 6) * 16;
#pragma unroll 4
    for (int j = 0; j < 16; ++j)
      smem[(rb + j) * 65 + col] = W[(size_t)(r0 + rb + j) * 256 + c0 + col];
    __syncthreads();
#pragma unroll 4
    for (int j = 0; j < 16; ++j)
      Wt[(size_t)(c0 + rb + j) * 256 + r0 + col] = (__bf16)smem[col * 65 + rb + j];
  }
}

// ---------------------------------------------------------------------------
// Kernel 2: fused g-MLP layers 2..4, one block per (image, object i)
//  512 threads = 8 waves: wave = (row-half mh, col-quarter nq)
//  Hs: 64 rows x 256 cols bf16, pitch 264 (528 B = 33*16 B)
//  MFMA operands swapped -> D regs span 4 consecutive cols -> b64 writebacks
// ---------------------------------------------------------------------------
#define HP 264

template <bool LAST>
__device__ __forceinline__ void g_layer(__bf16* Hs, const __bf16* __restrict__ Wt,
                                        const float* __restrict__ bias_g,
                                        int mh, int nq, int q, int r16,
                                        float* __restrict__ part_row) {
  f32x4 acc[2][4];
  const f32x4 z = {0.f, 0.f, 0.f, 0.f};
#pragma unroll
  for (int mt = 0; mt < 2; ++mt)
#pragma unroll
    for (int nt = 0; nt < 4; ++nt) acc[mt][nt] = z;

#pragma unroll 2
  for (int ks = 0; ks < 8; ++ks) {
    const int kof = ks * 32 + q * 8;
    bf16x8 a[2], b[4];
#pragma unroll
    for (int mt = 0; mt < 2; ++mt)
      a[mt] = *(const bf16x8*)(&Hs[(mh * 32 + mt * 16 + r16) * HP + kof]);
#pragma unroll
    for (int nt = 0; nt < 4; ++nt)
      b[nt] = *(const bf16x8*)(&Wt[(size_t)(nq * 64 + nt * 16 + r16) * 256 + kof]);
#pragma unroll
    for (int mt = 0; mt < 2; ++mt)
#pragma unroll
      for (int nt = 0; nt < 4; ++nt)
        // swapped operands: D[lane&15 -> row m][(lane>>4)*4+r -> col n]
        acc[mt][nt] = __builtin_amdgcn_mfma_f32_16x16x32_bf16(b[nt], a[mt], acc[mt][nt], 0, 0, 0);
  }

  if (!LAST) {
    __syncthreads();   // all waves done reading Hs
#pragma unroll
    for (int mt = 0; mt < 2; ++mt)
#pragma unroll
      for (int nt = 0; nt < 4; ++nt) {
        const int n0 = nq * 64 + nt * 16 + q * 4;
        const f32x4 bv = *(const f32x4*)&bias_g[n0];
        const f32x4 s = acc[mt][nt] + bv;
        bf16x4 h;
#pragma unroll
        for (int r = 0; r < 4; ++r) h[r] = (__bf16)fmaxf(s[r], 0.f);
        *(bf16x4*)(&Hs[(mh * 32 + mt * 16 + r16) * HP + n0]) = h;
      }
    __syncthreads();
  } else {
    // sum relu(acc+bias) over this wave's 32 rows, reduce over r16 lanes
    f32x4 s4[4];
#pragma unroll
    for (int nt = 0; nt < 4; ++nt) {
      const int n0 = nq * 64 + nt * 16 + q * 4;
      const f32x4 bv = *(const f32x4*)&bias_g[n0];
      f32x4 s;
#pragma unroll
      for (int r = 0; r < 4; ++r)
        s[r] = fmaxf(acc[0][nt][r] + bv[r], 0.f) + fmaxf(acc[1][nt][r] + bv[r], 0.f);
#pragma unroll
      for (int d = 1; d < 16; d <<= 1) {
#pragma unroll
        for (int r = 0; r < 4; ++r) s[r] += __shfl_xor(s[r], d, 64);
      }
      s4[nt] = s;
    }
    __syncthreads();                       // drain Hs reads; then reuse Hs as scratch
    float* scr = (float*)Hs;               // 256 floats
    if (mh == 1 && r16 == 0) {
#pragma unroll
      for (int nt = 0; nt < 4; ++nt)
        *(f32x4*)&scr[nq * 64 + nt * 16 + q * 4] = s4[nt];
    }
    __syncthreads();
    if (mh == 0 && r16 == 0) {
#pragma unroll
      for (int nt = 0; nt < 4; ++nt) {
        const int n0 = nq * 64 + nt * 16 + q * 4;
        const f32x4 o = s4[nt] + *(const f32x4*)&scr[n0];
        *(f32x4*)&part_row[n0] = o;
      }
    }
  }
}

__global__ __launch_bounds__(512, 5) void rn_main(
    const float* __restrict__ U, const float* __restrict__ V,
    const float* __restrict__ Qb,
    const __bf16* __restrict__ W2t, const __bf16* __restrict__ W3t,
    const __bf16* __restrict__ W4t,
    const float* __restrict__ b2, const float* __restrict__ b3,
    const float* __restrict__ b4,
    float* __restrict__ part) {
  __shared__ __align__(16) __bf16 Hs[64 * HP];   // 33792 B
  const int blk = blockIdx.x;
  const int nimg = blk >> 6, iobj = blk & 63;
  const int t = threadIdx.x;

  // phase 0: h1[j][:] = relu(U[n,i,:] + V[n,j,:] + Qb[n,:]) -> bf16 LDS
  {
    const int c = t & 63;          // col-quad: cols 4c..4c+3
    const int jb = (t >> 6) * 8;   // 8 rows
    const f32x4 u4 = *(const f32x4*)&U[(size_t)(nimg * 64 + iobj) * 256 + c * 4];
    const f32x4 q4 = *(const f32x4*)&Qb[(size_t)nimg * 256 + c * 4];
    const f32x4 uq = u4 + q4;
#pragma unroll
    for (int jj = 0; jj < 8; ++jj) {
      const f32x4 v4 = *(const f32x4*)&V[(size_t)(nimg * 64 + jb + jj) * 256 + c * 4];
      bf16x4 h;
#pragma unroll
      for (int r = 0; r < 4; ++r) h[r] = (__bf16)fmaxf(uq[r] + v4[r], 0.f);
      *(bf16x4*)(&Hs[(jb + jj) * HP + c * 4]) = h;
    }
  }
  __syncthreads();

  const int w = t >> 6, lane = t & 63;
  const int q = lane >> 4, r16 = lane & 15;
  const int mh = w >> 2, nq = w & 3;
  float* part_row = part + (size_t)blk * 256;

  g_layer<false>(Hs, W2t, b2, mh, nq, q, r16, part_row);
  g_layer<false>(Hs, W3t, b3, mh, nq, q, r16, part_row);
  g_layer<true >(Hs, W4t, b4, mh, nq, q, r16, part_row);
}

// ---------------------------------------------------------------------------
// Kernel 3: reduce partials -> context, f-MLP (fp32), log_softmax
// ---------------------------------------------------------------------------
__global__ __launch_bounds__(256) void rn_final(
    const float* __restrict__ part,
    const float* __restrict__ f_w1, const float* __restrict__ f_b1,
    const float* __restrict__ f_w2, const float* __restrict__ f_b2,
    const float* __restrict__ f_w3, const float* __restrict__ f_b3,
    float* __restrict__ out) {
  __shared__ float ctx[256], y1[256], y2[256], sc[2];
  const int n = blockIdx.x, t = threadIdx.x;

  float s = 0.f;
  for (int i = 0; i < 64; ++i) s += part[((size_t)n * 64 + i) * 256 + t];
  ctx[t] = s * (1.0f / 4096.0f);
  __syncthreads();

  float a = f_b1[t];
  for (int k = 0; k < 256; ++k) a += ctx[k] * f_w1[k * 256 + t];
  y1[t] = fmaxf(a, 0.f);
  __syncthreads();

  float b = f_b2[t];
  for (int k = 0; k < 256; ++k) b += y1[k] * f_w2[k * 256 + t];
  y2[t] = fmaxf(b, 0.f);
  __syncthreads();

  if (t < 2) {
    float c = f_b3[t];
    for (int k = 0; k < 256; ++k) c += y2[k] * f_w3[k * 2 + t];
    sc[t] = c;
  }
  __syncthreads();

  if (t == 0) {
    const float s0 = sc[0], s1 = sc[1];
    const float mx = fmaxf(s0, s1);
    const float lse = mx + logf(expf(s0 - mx) + expf(s1 - mx));
    out[n * 2 + 0] = s0 - lse;
    out[n * 2 + 1] = s1 - lse;
  }
}

// ---------------------------------------------------------------------------
extern "C" void kernel_launch(void* const* d_in, const int* in_sizes, int n_in,
                              void* d_out, int out_size, void* d_ws, size_t ws_size,
                              hipStream_t stream) {
  const float* img  = (const float*)d_in[0];
  const float* ques = (const float*)d_in[1];
  const float* g_w1 = (const float*)d_in[2];
  const float* g_b1 = (const float*)d_in[3];
  const float* g_w2 = (const float*)d_in[4];
  const float* g_b2 = (const float*)d_in[5];
  const float* g_w3 = (const float*)d_in[6];
  const float* g_b3 = (const float*)d_in[7];
  const float* g_w4 = (const float*)d_in[8];
  const float* g_b4 = (const float*)d_in[9];
  const float* f_w1 = (const float*)d_in[10];
  const float* f_b1 = (const float*)d_in[11];
  const float* f_w2 = (const float*)d_in[12];
  const float* f_b2 = (const float*)d_in[13];
  const float* f_w3 = (const float*)d_in[14];
  const float* f_b3 = (const float*)d_in[15];
  float* out = (float*)d_out;

  char* ws = (char*)d_ws;
  float*  U    = (float*)(ws);                                 // 4 MB
  float*  V    = (float*)(ws + (size_t)4  * 1048576);          // 4 MB
  float*  part = (float*)(ws + (size_t)8  * 1048576);          // 4 MB
  float*  Qb   = (float*)(ws + (size_t)12 * 1048576);          // 64 KB
  __bf16* W2t  = (__bf16*)(ws + (size_t)12 * 1048576 + 65536); // 128 KB each
  __bf16* W3t  = W2t + 65536;
  __bf16* W4t  = W3t + 65536;

  prep_kernel<<<368, 256, 0, stream>>>(img, ques, g_w1, g_b1, g_w2, g_w3, g_w4,
                                       U, V, Qb, W2t, W3t, W4t);
  rn_main<<<4096, 512, 0, stream>>>(U, V, Qb, W2t, W3t, W4t, g_b2, g_b3, g_b4, part);
  rn_final<<<64, 256, 0, stream>>>(part, f_w1, f_b1, f_w2, f_b2, f_w3, f_b3, out);
}

// Round 3
// 315.009 us; speedup vs baseline: 1.5695x; 1.5695x over previous
//
#include <hip/hip_runtime.h>
#include <hip/hip_bf16.h>

typedef __bf16 bf16x8 __attribute__((ext_vector_type(8)));
typedef __bf16 bf16x4 __attribute__((ext_vector_type(4)));
typedef float  f32x4  __attribute__((ext_vector_type(4)));

// ---------------------------------------------------------------------------
// Kernel 1: prep (unchanged from round 2 — passed validation)
//  blocks [0,256):   U,V — block = (image n, 16-object chunk); cells in LDS
//  blocks [256,320): Qb  — ques @ g_w1[132:388) + g_b1
//  blocks [320,368): bf16 transpose of g_w2/g_w3/g_w4 via LDS 64x64 tiles
// ---------------------------------------------------------------------------
__global__ __launch_bounds__(256) void prep_kernel(
    const float* __restrict__ img, const float* __restrict__ ques,
    const float* __restrict__ g_w1, const float* __restrict__ g_b1,
    const float* __restrict__ g_w2, const float* __restrict__ g_w3,
    const float* __restrict__ g_w4,
    float* __restrict__ U, float* __restrict__ V, float* __restrict__ Qb,
    __bf16* __restrict__ W2t, __bf16* __restrict__ W3t, __bf16* __restrict__ W4t) {
  __shared__ float smem[64 * 65];
  const int blk = blockIdx.x;
  const int t = threadIdx.x;

  if (blk < 256) {
    const int n = blk >> 2, obase = (blk & 3) * 16;
    for (int idx = t; idx < 66 * 16; idx += 256) {
      const int c = idx >> 4, o = obase + (idx & 15);
      float v;
      if (c < 64)      v = img[n * 4096 + c * 64 + o];
      else if (c == 64) v = (float)(o >> 3);
      else              v = (float)(o & 7);
      smem[idx] = v;
    }
    __syncthreads();
    float u[16], vv[16];
#pragma unroll
    for (int o = 0; o < 16; ++o) { u[o] = 0.f; vv[o] = 0.f; }
    for (int d = 0; d < 66; ++d) {
      const float wu = g_w1[d * 256 + t];
      const float wv = g_w1[(66 + d) * 256 + t];
#pragma unroll
      for (int o = 0; o < 16; ++o) {
        const float cc = smem[d * 16 + o];
        u[o]  += cc * wu;
        vv[o] += cc * wv;
      }
    }
#pragma unroll
    for (int o = 0; o < 16; ++o) {
      U[(size_t)(n * 64 + obase + o) * 256 + t] = u[o];
      V[(size_t)(n * 64 + obase + o) * 256 + t] = vv[o];
    }
  } else if (blk < 320) {
    const int n = blk - 256;
    smem[t] = ques[n * 256 + t];
    __syncthreads();
    float s = g_b1[t];
    for (int e = 0; e < 256; ++e) s += smem[e] * g_w1[(132 + e) * 256 + t];
    Qb[n * 256 + t] = s;
  } else {
    const int b2 = blk - 320;
    const int wsel = b2 >> 4;
    const int tile = b2 & 15;
    const int r0 = (tile >> 2) * 64, c0 = (tile & 3) * 64;
    const float* W = (wsel == 0) ? g_w2 : (wsel == 1) ? g_w3 : g_w4;
    __bf16* Wt    = (wsel == 0) ? W2t  : (wsel == 1) ? W3t  : W4t;
    const int col = t & 63, rb = (t >> 6) * 16;
#pragma unroll 4
    for (int j = 0; j < 16; ++j)
      smem[(rb + j) * 65 + col] = W[(size_t)(r0 + rb + j) * 256 + c0 + col];
    __syncthreads();
#pragma unroll 4
    for (int j = 0; j < 16; ++j)
      Wt[(size_t)(c0 + rb + j) * 256 + r0 + col] = (__bf16)smem[col * 65 + rb + j];
  }
}

// ---------------------------------------------------------------------------
// Kernel 2: fused g-MLP layers 2..4. Block = 512 thr / 8 waves, one (n,i).
//  Wave nq owns ALL 64 rows x 32-col strip -> no duplicated Wt loads.
//  acc = 4(m) x 2(nt) f32x4 = 32 regs; 1-deep B prefetch; target 4 waves/SIMD.
//  Hs: K-major skewed, exactly 32 KB: elem(row,c) =
//     (c>>3)*512 + ((row + (c>>3)) & 63)*8 + (c&7)
//  - phase-0 b64 writes: conflict-free (skew spreads kblk across banks)
//  - A-frag b128 reads: one full kblk row, 2-way (free)
//  - writeback b64: uniform bank spread
// ---------------------------------------------------------------------------
__device__ __forceinline__ int hidx(int row, int c) {
  const int kb = c >> 3;
  return kb * 512 + (((row + kb) & 63) << 3) + (c & 7);
}

template <bool LAST>
__device__ __forceinline__ void g_layer(__bf16* Hs, const __bf16* __restrict__ Wt,
                                        const float* __restrict__ bias_g,
                                        int nq, int q, int r16,
                                        float* __restrict__ part_row) {
  f32x4 acc[4][2];
  const f32x4 z = {0.f, 0.f, 0.f, 0.f};
#pragma unroll
  for (int m = 0; m < 4; ++m)
#pragma unroll
    for (int nt = 0; nt < 2; ++nt) acc[m][nt] = z;

  // B base: row (output col) = nq*32 + nt*16 + r16, K offset q*8 within ks*32
  const __bf16* wbase = Wt + (size_t)(nq * 32 + r16) * 256 + q * 8;

  bf16x8 b[2], bn[2];
  b[0] = *(const bf16x8*)(wbase);
  b[1] = *(const bf16x8*)(wbase + 16 * 256);

#pragma unroll
  for (int ks = 0; ks < 8; ++ks) {
    const int kb = ks * 4 + q;                 // kof = ks*32 + q*8 -> kblk
    bf16x8 a[4];
#pragma unroll
    for (int m = 0; m < 4; ++m) {
      const int row = m * 16 + r16;
      a[m] = *(const bf16x8*)(&Hs[kb * 512 + (((row + kb) & 63) << 3)]);
    }
    if (ks < 7) {
      bn[0] = *(const bf16x8*)(wbase + (ks + 1) * 32);
      bn[1] = *(const bf16x8*)(wbase + 16 * 256 + (ks + 1) * 32);
    }
#pragma unroll
    for (int m = 0; m < 4; ++m)
#pragma unroll
      for (int nt = 0; nt < 2; ++nt)
        // swapped operands (verified r2): acc[m][nt] covers
        // row = m*16 + r16, cols = nq*32 + nt*16 + q*4 + reg
        acc[m][nt] = __builtin_amdgcn_mfma_f32_16x16x32_bf16(b[nt], a[m], acc[m][nt], 0, 0, 0);
    b[0] = bn[0];
    b[1] = bn[1];
  }

  f32x4 bv[2];
#pragma unroll
  for (int nt = 0; nt < 2; ++nt)
    bv[nt] = *(const f32x4*)&bias_g[nq * 32 + nt * 16 + q * 4];

  if (!LAST) {
    __syncthreads();   // all waves done reading Hs
#pragma unroll
    for (int m = 0; m < 4; ++m)
#pragma unroll
      for (int nt = 0; nt < 2; ++nt) {
        const int cb = nq * 32 + nt * 16 + q * 4;
        const f32x4 s = acc[m][nt] + bv[nt];
        bf16x4 h;
#pragma unroll
        for (int r = 0; r < 4; ++r) h[r] = (__bf16)fmaxf(s[r], 0.f);
        *(bf16x4*)(&Hs[hidx(m * 16 + r16, cb)]) = h;
      }
    __syncthreads();
  } else {
    // each wave owns distinct cols -> pure in-wave reduction, no barriers
#pragma unroll
    for (int nt = 0; nt < 2; ++nt) {
      const int cb = nq * 32 + nt * 16 + q * 4;
      f32x4 s;
#pragma unroll
      for (int r = 0; r < 4; ++r)
        s[r] = fmaxf(acc[0][nt][r] + bv[nt][r], 0.f)
             + fmaxf(acc[1][nt][r] + bv[nt][r], 0.f)
             + fmaxf(acc[2][nt][r] + bv[nt][r], 0.f)
             + fmaxf(acc[3][nt][r] + bv[nt][r], 0.f);
#pragma unroll
      for (int d = 1; d < 16; d <<= 1) {
#pragma unroll
        for (int r = 0; r < 4; ++r) s[r] += __shfl_xor(s[r], d, 64);
      }
      if (r16 == 0) *(f32x4*)&part_row[cb] = s;
    }
  }
}

__global__ __launch_bounds__(512, 4) void rn_main(
    const float* __restrict__ U, const float* __restrict__ V,
    const float* __restrict__ Qb,
    const __bf16* __restrict__ W2t, const __bf16* __restrict__ W3t,
    const __bf16* __restrict__ W4t,
    const float* __restrict__ b2, const float* __restrict__ b3,
    const float* __restrict__ b4,
    float* __restrict__ part) {
  __shared__ __align__(16) __bf16 Hs[16384];   // exactly 32 KB
  const int blk = blockIdx.x;
  const int nimg = blk >> 6, iobj = blk & 63;
  const int t = threadIdx.x;

  // phase 0: h1[j][:] = relu(U[n,i,:] + V[n,j,:] + Qb[n,:]) -> bf16 LDS
  {
    const int c4 = t & 63;         // col-quad: cols 4*c4 .. 4*c4+3
    const int jb = (t >> 6) * 8;   // 8 rows per thread
    const f32x4 u4 = *(const f32x4*)&U[(size_t)(nimg * 64 + iobj) * 256 + c4 * 4];
    const f32x4 q4 = *(const f32x4*)&Qb[(size_t)nimg * 256 + c4 * 4];
    const f32x4 uq = u4 + q4;
#pragma unroll
    for (int jj = 0; jj < 8; ++jj) {
      const int row = jb + jj;
      const f32x4 v4 = *(const f32x4*)&V[(size_t)(nimg * 64 + row) * 256 + c4 * 4];
      bf16x4 h;
#pragma unroll
      for (int r = 0; r < 4; ++r) h[r] = (__bf16)fmaxf(uq[r] + v4[r], 0.f);
      *(bf16x4*)(&Hs[hidx(row, c4 * 4)]) = h;
    }
  }
  __syncthreads();

  const int nq = t >> 6;               // wave id = 32-col strip
  const int lane = t & 63;
  const int q = lane >> 4, r16 = lane & 15;
  float* part_row = part + (size_t)blk * 256;

  g_layer<false>(Hs, W2t, b2, nq, q, r16, part_row);
  g_layer<false>(Hs, W3t, b3, nq, q, r16, part_row);
  g_layer<true >(Hs, W4t, b4, nq, q, r16, part_row);
}

// ---------------------------------------------------------------------------
// Kernel 3: reduce partials -> context, f-MLP (fp32), log_softmax
// ---------------------------------------------------------------------------
__global__ __launch_bounds__(256) void rn_final(
    const float* __restrict__ part,
    const float* __restrict__ f_w1, const float* __restrict__ f_b1,
    const float* __restrict__ f_w2, const float* __restrict__ f_b2,
    const float* __restrict__ f_w3, const float* __restrict__ f_b3,
    float* __restrict__ out) {
  __shared__ float ctx[256], y1[256], y2[256], sc[2];
  const int n = blockIdx.x, t = threadIdx.x;

  float s = 0.f;
  for (int i = 0; i < 64; ++i) s += part[((size_t)n * 64 + i) * 256 + t];
  ctx[t] = s * (1.0f / 4096.0f);
  __syncthreads();

  float a = f_b1[t];
  for (int k = 0; k < 256; ++k) a += ctx[k] * f_w1[k * 256 + t];
  y1[t] = fmaxf(a, 0.f);
  __syncthreads();

  float b = f_b2[t];
  for (int k = 0; k < 256; ++k) b += y1[k] * f_w2[k * 256 + t];
  y2[t] = fmaxf(b, 0.f);
  __syncthreads();

  if (t < 2) {
    float c = f_b3[t];
    for (int k = 0; k < 256; ++k) c += y2[k] * f_w3[k * 2 + t];
    sc[t] = c;
  }
  __syncthreads();

  if (t == 0) {
    const float s0 = sc[0], s1 = sc[1];
    const float mx = fmaxf(s0, s1);
    const float lse = mx + logf(expf(s0 - mx) + expf(s1 - mx));
    out[n * 2 + 0] = s0 - lse;
    out[n * 2 + 1] = s1 - lse;
  }
}

// ---------------------------------------------------------------------------
extern "C" void kernel_launch(void* const* d_in, const int* in_sizes, int n_in,
                              void* d_out, int out_size, void* d_ws, size_t ws_size,
                              hipStream_t stream) {
  const float* img  = (const float*)d_in[0];
  const float* ques = (const float*)d_in[1];
  const float* g_w1 = (const float*)d_in[2];
  const float* g_b1 = (const float*)d_in[3];
  const float* g_w2 = (const float*)d_in[4];
  const float* g_b2 = (const float*)d_in[5];
  const float* g_w3 = (const float*)d_in[6];
  const float* g_b3 = (const float*)d_in[7];
  const float* g_w4 = (const float*)d_in[8];
  const float* g_b4 = (const float*)d_in[9];
  const float* f_w1 = (const float*)d_in[10];
  const float* f_b1 = (const float*)d_in[11];
  const float* f_w2 = (const float*)d_in[12];
  const float* f_b2 = (const float*)d_in[13];
  const float* f_w3 = (const float*)d_in[14];
  const float* f_b3 = (const float*)d_in[15];
  float* out = (float*)d_out;

  char* ws = (char*)d_ws;
  float*  U    = (float*)(ws);                                 // 4 MB
  float*  V    = (float*)(ws + (size_t)4  * 1048576);          // 4 MB
  float*  part = (float*)(ws + (size_t)8  * 1048576);          // 4 MB
  float*  Qb   = (float*)(ws + (size_t)12 * 1048576);          // 64 KB
  __bf16* W2t  = (__bf16*)(ws + (size_t)12 * 1048576 + 65536); // 128 KB each
  __bf16* W3t  = W2t + 65536;
  __bf16* W4t  = W3t + 65536;

  prep_kernel<<<368, 256, 0, stream>>>(img, ques, g_w1, g_b1, g_w2, g_w3, g_w4,
                                       U, V, Qb, W2t, W3t, W4t);
  rn_main<<<4096, 512, 0, stream>>>(U, V, Qb, W2t, W3t, W4t, g_b2, g_b3, g_b4, part);
  rn_final<<<64, 256, 0, stream>>>(part, f_w1, f_b1, f_w2, f_b2, f_w3, f_b3, out);
}

// Round 4
// 307.965 us; speedup vs baseline: 1.6054x; 1.0229x over previous
//
#include <hip/hip_runtime.h>
#include <hip/hip_bf16.h>

typedef __bf16 bf16x8 __attribute__((ext_vector_type(8)));
typedef __bf16 bf16x4 __attribute__((ext_vector_type(4)));
typedef float  f32x4  __attribute__((ext_vector_type(4)));

// ---------------------------------------------------------------------------
// Kernel 1: prep (unchanged — validated)
// ---------------------------------------------------------------------------
__global__ __launch_bounds__(256) void prep_kernel(
    const float* __restrict__ img, const float* __restrict__ ques,
    const float* __restrict__ g_w1, const float* __restrict__ g_b1,
    const float* __restrict__ g_w2, const float* __restrict__ g_w3,
    const float* __restrict__ g_w4,
    float* __restrict__ U, float* __restrict__ V, float* __restrict__ Qb,
    __bf16* __restrict__ W2t, __bf16* __restrict__ W3t, __bf16* __restrict__ W4t) {
  __shared__ float smem[64 * 65];
  const int blk = blockIdx.x;
  const int t = threadIdx.x;

  if (blk < 256) {
    const int n = blk >> 2, obase = (blk & 3) * 16;
    for (int idx = t; idx < 66 * 16; idx += 256) {
      const int c = idx >> 4, o = obase + (idx & 15);
      float v;
      if (c < 64)      v = img[n * 4096 + c * 64 + o];
      else if (c == 64) v = (float)(o >> 3);
      else              v = (float)(o & 7);
      smem[idx] = v;
    }
    __syncthreads();
    float u[16], vv[16];
#pragma unroll
    for (int o = 0; o < 16; ++o) { u[o] = 0.f; vv[o] = 0.f; }
    for (int d = 0; d < 66; ++d) {
      const float wu = g_w1[d * 256 + t];
      const float wv = g_w1[(66 + d) * 256 + t];
#pragma unroll
      for (int o = 0; o < 16; ++o) {
        const float cc = smem[d * 16 + o];
        u[o]  += cc * wu;
        vv[o] += cc * wv;
      }
    }
#pragma unroll
    for (int o = 0; o < 16; ++o) {
      U[(size_t)(n * 64 + obase + o) * 256 + t] = u[o];
      V[(size_t)(n * 64 + obase + o) * 256 + t] = vv[o];
    }
  } else if (blk < 320) {
    const int n = blk - 256;
    smem[t] = ques[n * 256 + t];
    __syncthreads();
    float s = g_b1[t];
    for (int e = 0; e < 256; ++e) s += smem[e] * g_w1[(132 + e) * 256 + t];
    Qb[n * 256 + t] = s;
  } else {
    const int b2 = blk - 320;
    const int wsel = b2 >> 4;
    const int tile = b2 & 15;
    const int r0 = (tile >> 2) * 64, c0 = (tile & 3) * 64;
    const float* W = (wsel == 0) ? g_w2 : (wsel == 1) ? g_w3 : g_w4;
    __bf16* Wt    = (wsel == 0) ? W2t  : (wsel == 1) ? W3t  : W4t;
    const int col = t & 63, rb = (t >> 6) * 16;
#pragma unroll 4
    for (int j = 0; j < 16; ++j)
      smem[(rb + j) * 65 + col] = W[(size_t)(r0 + rb + j) * 256 + c0 + col];
    __syncthreads();
#pragma unroll 4
    for (int j = 0; j < 16; ++j)
      Wt[(size_t)(c0 + rb + j) * 256 + r0 + col] = (__bf16)smem[col * 65 + rb + j];
  }
}

// ---------------------------------------------------------------------------
// Kernel 2: fused g-MLP layers 2..4. 512 thr / 8 waves, one (n,i) per block.
//  - wave nq owns all 64 rows x 32-col strip (no duplicated W loads)
//  - 4-deep rolling B-prefetch ring, rolls ACROSS layer boundaries
//  - Hs ping-pong (2 x 32 KB): no pre-writeback barrier; 3 barriers/block
//  Hs elem(row,c) = (c>>3)*512 + ((row+(c>>3))&63)*8 + (c&7)
// ---------------------------------------------------------------------------
#define HSZ 16384   // bf16 elems per buffer (32 KB)

__device__ __forceinline__ int hidx(int row, int c) {
  const int kb = c >> 3;
  return kb * 512 + (((row + kb) & 63) << 3) + (c & 7);
}

template <bool LAST>
__device__ __forceinline__ void g_layer(const __bf16* Hcur, __bf16* Hnxt,
                                        bf16x8 ring[4][2],
                                        const __bf16* __restrict__ wcur,
                                        const __bf16* __restrict__ wnext,
                                        const float* __restrict__ bias_g,
                                        int nq, int q, int r16,
                                        float* __restrict__ part_row) {
  f32x4 acc[4][2];
  const f32x4 z = {0.f, 0.f, 0.f, 0.f};
#pragma unroll
  for (int m = 0; m < 4; ++m)
#pragma unroll
    for (int nt = 0; nt < 2; ++nt) acc[m][nt] = z;

#pragma unroll
  for (int ks = 0; ks < 8; ++ks) {
    const int kb = ks * 4 + q;
    bf16x8 a[4];
#pragma unroll
    for (int m = 0; m < 4; ++m) {
      const int row = m * 16 + r16;
      a[m] = *(const bf16x8*)(&Hcur[kb * 512 + (((row + kb) & 63) << 3)]);
    }
    const bf16x8 b0 = ring[ks & 3][0];
    const bf16x8 b1 = ring[ks & 3][1];
    // refill slot: 4 iterations ahead (crosses into next layer's W)
    if (ks < 4) {
      ring[ks & 3][0] = *(const bf16x8*)(wcur + (ks + 4) * 32);
      ring[ks & 3][1] = *(const bf16x8*)(wcur + 4096 + (ks + 4) * 32);
    } else if (!LAST) {
      ring[ks & 3][0] = *(const bf16x8*)(wnext + (ks - 4) * 32);
      ring[ks & 3][1] = *(const bf16x8*)(wnext + 4096 + (ks - 4) * 32);
    }
#pragma unroll
    for (int m = 0; m < 4; ++m) {
      // swapped operands (verified): acc[m][nt] -> row m*16+r16,
      // cols nq*32 + nt*16 + q*4 + reg
      acc[m][0] = __builtin_amdgcn_mfma_f32_16x16x32_bf16(b0, a[m], acc[m][0], 0, 0, 0);
      acc[m][1] = __builtin_amdgcn_mfma_f32_16x16x32_bf16(b1, a[m], acc[m][1], 0, 0, 0);
    }
  }

  f32x4 bv[2];
#pragma unroll
  for (int nt = 0; nt < 2; ++nt)
    bv[nt] = *(const f32x4*)&bias_g[nq * 32 + nt * 16 + q * 4];

  if (!LAST) {
    // write other buffer: no barrier needed before
#pragma unroll
    for (int m = 0; m < 4; ++m)
#pragma unroll
      for (int nt = 0; nt < 2; ++nt) {
        const int cb = nq * 32 + nt * 16 + q * 4;
        const f32x4 s = acc[m][nt] + bv[nt];
        bf16x4 h;
#pragma unroll
        for (int r = 0; r < 4; ++r) h[r] = (__bf16)fmaxf(s[r], 0.f);
        *(bf16x4*)(&Hnxt[hidx(m * 16 + r16, cb)]) = h;
      }
    __syncthreads();
  } else {
#pragma unroll
    for (int nt = 0; nt < 2; ++nt) {
      const int cb = nq * 32 + nt * 16 + q * 4;
      f32x4 s;
#pragma unroll
      for (int r = 0; r < 4; ++r)
        s[r] = fmaxf(acc[0][nt][r] + bv[nt][r], 0.f)
             + fmaxf(acc[1][nt][r] + bv[nt][r], 0.f)
             + fmaxf(acc[2][nt][r] + bv[nt][r], 0.f)
             + fmaxf(acc[3][nt][r] + bv[nt][r], 0.f);
#pragma unroll
      for (int d = 1; d < 16; d <<= 1) {
#pragma unroll
        for (int r = 0; r < 4; ++r) s[r] += __shfl_xor(s[r], d, 64);
      }
      if (r16 == 0) *(f32x4*)&part_row[cb] = s;
    }
  }
}

__global__ __launch_bounds__(512, 4) void rn_main(
    const float* __restrict__ U, const float* __restrict__ V,
    const float* __restrict__ Qb,
    const __bf16* __restrict__ W2t, const __bf16* __restrict__ W3t,
    const __bf16* __restrict__ W4t,
    const float* __restrict__ b2, const float* __restrict__ b3,
    const float* __restrict__ b4,
    float* __restrict__ part) {
  __shared__ __align__(16) __bf16 Hs[2 * HSZ];   // 64 KB
  const int blk = blockIdx.x;
  const int nimg = blk >> 6, iobj = blk & 63;
  const int t = threadIdx.x;
  const int nq = t >> 6, lane = t & 63;
  const int q = lane >> 4, r16 = lane & 15;

  // per-wave W base pointers (row = output col = nq*32 [+16] + r16, K off q*8)
  const size_t woff = (size_t)(nq * 32 + r16) * 256 + q * 8;
  const __bf16* w2 = W2t + woff;
  const __bf16* w3 = W3t + woff;
  const __bf16* w4 = W4t + woff;

  // start layer-2 B ring fill immediately (overlaps phase-0 loads/math)
  bf16x8 ring[4][2];
#pragma unroll
  for (int d = 0; d < 4; ++d) {
    ring[d][0] = *(const bf16x8*)(w2 + d * 32);
    ring[d][1] = *(const bf16x8*)(w2 + 4096 + d * 32);
  }

  // phase 0: h1[j][:] = relu(U[n,i,:] + V[n,j,:] + Qb[n,:]) -> Hs buf 0
  {
    const int c4 = t & 63;
    const int jb = (t >> 6) * 8;
    const f32x4 u4 = *(const f32x4*)&U[(size_t)(nimg * 64 + iobj) * 256 + c4 * 4];
    const f32x4 q4 = *(const f32x4*)&Qb[(size_t)nimg * 256 + c4 * 4];
    const f32x4 uq = u4 + q4;
#pragma unroll
    for (int jj = 0; jj < 8; ++jj) {
      const int row = jb + jj;
      const f32x4 v4 = *(const f32x4*)&V[(size_t)(nimg * 64 + row) * 256 + c4 * 4];
      bf16x4 h;
#pragma unroll
      for (int r = 0; r < 4; ++r) h[r] = (__bf16)fmaxf(uq[r] + v4[r], 0.f);
      *(bf16x4*)(&Hs[hidx(row, c4 * 4)]) = h;
    }
  }
  __syncthreads();

  float* part_row = part + (size_t)blk * 256;

  g_layer<false>(Hs,       Hs + HSZ, ring, w2, w3, b2, nq, q, r16, part_row);
  g_layer<false>(Hs + HSZ, Hs,       ring, w3, w4, b3, nq, q, r16, part_row);
  g_layer<true >(Hs,       Hs + HSZ, ring, w4, w4, b4, nq, q, r16, part_row);
}

// ---------------------------------------------------------------------------
// Kernel 3: reduce partials -> context, f-MLP (fp32), log_softmax
// ---------------------------------------------------------------------------
__global__ __launch_bounds__(256) void rn_final(
    const float* __restrict__ part,
    const float* __restrict__ f_w1, const float* __restrict__ f_b1,
    const float* __restrict__ f_w2, const float* __restrict__ f_b2,
    const float* __restrict__ f_w3, const float* __restrict__ f_b3,
    float* __restrict__ out) {
  __shared__ float ctx[256], y1[256], y2[256], sc[2];
  const int n = blockIdx.x, t = threadIdx.x;

  float s = 0.f;
  for (int i = 0; i < 64; ++i) s += part[((size_t)n * 64 + i) * 256 + t];
  ctx[t] = s * (1.0f / 4096.0f);
  __syncthreads();

  float a = f_b1[t];
  for (int k = 0; k < 256; ++k) a += ctx[k] * f_w1[k * 256 + t];
  y1[t] = fmaxf(a, 0.f);
  __syncthreads();

  float b = f_b2[t];
  for (int k = 0; k < 256; ++k) b += y1[k] * f_w2[k * 256 + t];
  y2[t] = fmaxf(b, 0.f);
  __syncthreads();

  if (t < 2) {
    float c = f_b3[t];
    for (int k = 0; k < 256; ++k) c += y2[k] * f_w3[k * 2 + t];
    sc[t] = c;
  }
  __syncthreads();

  if (t == 0) {
    const float s0 = sc[0], s1 = sc[1];
    const float mx = fmaxf(s0, s1);
    const float lse = mx + logf(expf(s0 - mx) + expf(s1 - mx));
    out[n * 2 + 0] = s0 - lse;
    out[n * 2 + 1] = s1 - lse;
  }
}

// ---------------------------------------------------------------------------
extern "C" void kernel_launch(void* const* d_in, const int* in_sizes, int n_in,
                              void* d_out, int out_size, void* d_ws, size_t ws_size,
                              hipStream_t stream) {
  const float* img  = (const float*)d_in[0];
  const float* ques = (const float*)d_in[1];
  const float* g_w1 = (const float*)d_in[2];
  const float* g_b1 = (const float*)d_in[3];
  const float* g_w2 = (const float*)d_in[4];
  const float* g_b2 = (const float*)d_in[5];
  const float* g_w3 = (const float*)d_in[6];
  const float* g_b3 = (const float*)d_in[7];
  const float* g_w4 = (const float*)d_in[8];
  const float* g_b4 = (const float*)d_in[9];
  const float* f_w1 = (const float*)d_in[10];
  const float* f_b1 = (const float*)d_in[11];
  const float* f_w2 = (const float*)d_in[12];
  const float* f_b2 = (const float*)d_in[13];
  const float* f_w3 = (const float*)d_in[14];
  const float* f_b3 = (const float*)d_in[15];
  float* out = (float*)d_out;

  char* ws = (char*)d_ws;
  float*  U    = (float*)(ws);                                 // 4 MB
  float*  V    = (float*)(ws + (size_t)4  * 1048576);          // 4 MB
  float*  part = (float*)(ws + (size_t)8  * 1048576);          // 4 MB
  float*  Qb   = (float*)(ws + (size_t)12 * 1048576);          // 64 KB
  __bf16* W2t  = (__bf16*)(ws + (size_t)12 * 1048576 + 65536); // 128 KB each
  __bf16* W3t  = W2t + 65536;
  __bf16* W4t  = W3t + 65536;

  prep_kernel<<<368, 256, 0, stream>>>(img, ques, g_w1, g_b1, g_w2, g_w3, g_w4,
                                       U, V, Qb, W2t, W3t, W4t);
  rn_main<<<4096, 512, 0, stream>>>(U, V, Qb, W2t, W3t, W4t, g_b2, g_b3, g_b4, part);
  rn_final<<<64, 256, 0, stream>>>(part, f_w1, f_b1, f_w2, f_b2, f_w3, f_b3, out);
}